// Round 6
// baseline (7264.977 us; speedup 1.0000x reference)
//
#include <hip/hip_runtime.h>
#include <stdint.h>
#include <stddef.h>

typedef __bf16 bf16_t;
typedef bf16_t bf16x8 __attribute__((ext_vector_type(8)));
typedef bf16_t bf16x4 __attribute__((ext_vector_type(4)));
typedef float  f32x4  __attribute__((ext_vector_type(4)));

#define T_STEPS 2028
#define SEQ     2048
#define CIN     32
#define NGR     4      // batch groups (16 batches each)
#define MBB     16     // batch per group
#define CH      32     // chunk steps
#define NCH     64     // ceil(2028/32)
#define RING    4      // ring depth in chunks
#define XCH     (512*512)     // bf16 elems per xring slot: [512 stepbatch][512 col']
#define YSL     (32*4*64*8)   // bf16 elems per yring slot: [32 steps][4 kt][64 lane][8]

// workspace layout (bytes); ~41.5 MB
#define OFF_EFFW   0u          // bf16 [512][640]  (permuted gate rows)
#define OFF_BIAS   655360u     // f32  [4][512]    (permuted; l0 includes proj_b@w_ih0)
#define OFF_WHH    663552u     // bf16 [4][512][128] (permuted)
#define OFF_WIH    1187840u    // bf16 [3][512][128] (permuted, layers 1..3)
#define OFF_CNT    1613824u    // u32  counters, 64B-strided (44 used)
#define OFF_XRING  1638400u    // bf16 [4 layers][NGR][RING][512][512]
#define OFF_YRING  35192832u   // bf16 [3 layers][NGR][RING][YSL]  (h ring)

// permuted gate row p -> original LSTM row: gate r=p&3; unit u=(p>>7)*32+((p>>2)&3)*8+((p>>4)&7)
// => recur wave w=(p>>7), lane (q=(p>>2)&3, ln) holds gates of unit u=w*32+q*8+mt in acc[mt].
__device__ __host__ __forceinline__ int orig_row(int p) {
  return (p & 3) * 128 + ((p >> 7) * 32 + ((p >> 2) & 3) * 8 + ((p >> 4) & 7));
}
// xring column permutation: col'(p) = (p>>7)*128 + ((p>>2)&3)*32 + ((p>>4)&7)*4 + (p&3)
// -> consumer lane (w,q) reads its 32 gate-values CONTIGUOUS at w*128+q*32.

__device__ __forceinline__ int endk(int k) {
  int e = (k + 1) * CH;
  return e > T_STEPS ? T_STEPS : e;
}

__device__ __forceinline__ void spin_ge(uint32_t* p, uint32_t tgt) {
  while (atomicAdd(p, 0u) < tgt) __builtin_amdgcn_s_sleep(2);
}
__device__ __forceinline__ void publish(uint32_t* p, uint32_t v) {
  __builtin_amdgcn_fence(__ATOMIC_RELEASE, "agent");
  atomicMax(p, v);
}

__device__ __forceinline__ float fsigm(float x) {
  return __builtin_amdgcn_rcpf(1.0f + __builtin_amdgcn_exp2f(x * -1.44269504089f));
}
__device__ __forceinline__ float ftanh(float x) {
  return 1.0f - 2.0f * __builtin_amdgcn_rcpf(1.0f + __builtin_amdgcn_exp2f(x * 2.88539008178f));
}

__device__ __forceinline__ bf16x8 ldg8(const bf16_t* p) { return *(const bf16x8*)p; }

__device__ __forceinline__ bf16x8 ldg_cvt8(const float* p) {
  const f32x4 a = *(const f32x4*)p;
  const f32x4 b = *(const f32x4*)(p + 4);
  bf16x8 r;
  r[0] = (bf16_t)a[0]; r[1] = (bf16_t)a[1]; r[2] = (bf16_t)a[2]; r[3] = (bf16_t)a[3];
  r[4] = (bf16_t)b[0]; r[5] = (bf16_t)b[1]; r[6] = (bf16_t)b[2]; r[7] = (bf16_t)b[3];
  return r;
}

__device__ __forceinline__ bf16x4 pack4(f32x4 a) {
  bf16x4 v;
  v[0] = (bf16_t)a[0]; v[1] = (bf16_t)a[1]; v[2] = (bf16_t)a[2]; v[3] = (bf16_t)a[3];
  return v;
}

#define MFMA16(a, b, c) __builtin_amdgcn_mfma_f32_16x16x32_bf16((a), (b), (c), 0, 0, 0)

// ---------------- prep: permute weights, biases, zero counters ----------------
__global__ void k_prep_misc(const float* __restrict__ w_hh0,
                            const float* __restrict__ w_ih_rest,
                            const float* __restrict__ w_hh_rest,
                            const float* __restrict__ b_ih_rest,
                            const float* __restrict__ b_hh_rest,
                            uint8_t* __restrict__ ws) {
  const int bid = blockIdx.x;          // 2048 blocks
  const int l = bid >> 9;              // 0..3
  const int p = bid & 511;
  const int orig = orig_row(p);
  const int tid = threadIdx.x;         // 128 threads
  bf16_t* whh = (bf16_t*)(ws + OFF_WHH);
  bf16_t* wih = (bf16_t*)(ws + OFF_WIH);
  float* bias = (float*)(ws + OFF_BIAS);
  const float* src = (l == 0) ? (w_hh0 + orig * 128)
                              : (w_hh_rest + ((size_t)(l - 1) * 512 + orig) * 128);
  whh[((size_t)l * 512 + p) * 128 + tid] = (bf16_t)src[tid];
  if (l < 3)
    wih[((size_t)l * 512 + p) * 128 + tid] = (bf16_t)w_ih_rest[((size_t)l * 512 + orig) * 128 + tid];
  if (l >= 1 && tid == 0)
    bias[l * 512 + p] = b_ih_rest[(l - 1) * 512 + orig] + b_hh_rest[(l - 1) * 512 + orig];
  if (bid == 0) {
    uint32_t* cnt = (uint32_t*)(ws + OFF_CNT);
    for (int i = tid; i < 44 * 16; i += 128) cnt[i] = 0;
  }
}

// eff_w = w_ih0 @ proj_w (fused proj+layer0-input), eff_b -> bias[0]
__global__ void k_prep_effw(const float* __restrict__ proj_w,
                            const float* __restrict__ proj_b,
                            const float* __restrict__ w_ih0,
                            const float* __restrict__ b_ih0,
                            const float* __restrict__ b_hh0,
                            uint8_t* __restrict__ ws) {
  __shared__ float wr[320];
  const int p = blockIdx.x;            // 512 blocks
  const int orig = orig_row(p);
  const int tid = threadIdx.x;         // 256 threads
  for (int i = tid; i < 320; i += 256) wr[i] = w_ih0[(size_t)orig * 320 + i];
  __syncthreads();
  bf16_t* effw = (bf16_t*)(ws + OFF_EFFW);
  for (int kk = tid; kk < 640; kk += 256) {
    float a = 0.f;
    for (int z = 0; z < 320; ++z) a += wr[z] * proj_w[(size_t)z * 640 + kk];
    effw[(size_t)p * 640 + kk] = (bf16_t)a;
  }
  if (tid == 0) {
    float a = 0.f;
    for (int z = 0; z < 320; ++z) a += wr[z] * proj_b[z];
    ((float*)(ws + OFF_BIAS))[p] = a + b_ih0[orig] + b_hh0[orig];
  }
}

// ---------------- persistent pipeline: 44 blocks x 256 threads ----------------
// blocks 0..15  : conv   (mq = b>>2 owns permuted rows mq*128.., g = b&3) -> xring0 (+bias)
// blocks 16..31 : recur  (l = (b-16)>>2, g = b&3); holds ONLY w_hh resident (128 VGPR).
//                 Per step: 4 ds_read_b128 -> 32 MFMA -> in-lane act (8 units) -> 1 ds_write_b128
//                 + posted h store to yring. No gate_buf, no second weight array (rounds 3-5 lesson:
//                 256-reg weight demand does not fit; compiler reloads on the serial chain).
// blocks 32..43 : gemm   (l = 1+(b-32)>>2, g = b&3): x_pre_l = W_ih_l @ h_{l-1} from yring (+bias),
//                 one chunk behind recur_{l-1} -- off the serial chain, idle CUs.
// counters: conv mq*4+g (0..15); recur 16+l*4+g; gemm 32+(l-1)*4+g.
__global__ __launch_bounds__(256, 1) void k_pipeline(const float* __restrict__ in,
                                                     const float* __restrict__ out_w,
                                                     const float* __restrict__ out_b,
                                                     float* __restrict__ out,
                                                     uint8_t* __restrict__ ws) {
  __shared__ __align__(16) bf16_t hfrag[2][4][64][8];  // [buf][kt][lane q*16+ln][e]
  __shared__ float hfl[MBB][128];                      // final h (f32) for output head

  const int b = blockIdx.x;
  const int tid = threadIdx.x;
  const int w = tid >> 6;              // wave 0..3
  const int lane = tid & 63;
  const int q = lane >> 4;             // 0..3
  const int ln = lane & 15;            // 0..15 (= batch col)

  uint32_t* cnt = (uint32_t*)(ws + OFF_CNT);
  bf16_t* xring = (bf16_t*)(ws + OFF_XRING);
  bf16_t* yring = (bf16_t*)(ws + OFF_YRING);
  const float* bias = (const float*)(ws + OFF_BIAS);

  if (b < 16) {
    // ---- conv: permuted rows mq*128.. for group g -> xring0, bias pre-added ----
    const int mq = b >> 2, g = b & 3;
    const bf16_t* effw = (const bf16_t*)(ws + OFF_EFFW);
    f32x4 cb[8];
#pragma unroll
    for (int i = 0; i < 8; ++i)
      cb[i] = *(const f32x4*)(bias + mq * 128 + i * 16 + q * 4);
    uint32_t* my = cnt + (mq * 4 + g) * 16;
    uint32_t* guard = cnt + (16 + 0 * 4 + g) * 16;   // recur0 progress (ring free)
    for (int k = 0; k < NCH; ++k) {
      if (tid == 0 && k >= RING) spin_ge(guard, (uint32_t)endk(k - RING));
      __syncthreads();
      const int t0 = k * CH;
      bf16_t* xs = xring + (size_t)((0 * NGR + g) * RING + (k & 3)) * XCH;
      for (int mb = 0; mb < 2; ++mb) {
        f32x4 acc[4][8];
#pragma unroll
        for (int mi = 0; mi < 4; ++mi)
#pragma unroll
          for (int j = 0; j < 8; ++j) acc[mi][j] = (f32x4){0.f, 0.f, 0.f, 0.f};
#pragma unroll 4
        for (int kt = 0; kt < 20; ++kt) {        // kt == window offset
          bf16x8 bfr[8];
#pragma unroll
          for (int j = 0; j < 8; ++j) {
            int tt = t0 + w * 8 + j;
            if (tt > T_STEPS - 1) tt = T_STEPS - 1;
            bfr[j] = ldg_cvt8(in + (size_t)((g * MBB + ln) * SEQ + tt + kt) * CIN + q * 8);
          }
#pragma unroll
          for (int mi = 0; mi < 4; ++mi) {
            bf16x8 afr = ldg8(effw + (size_t)(mq * 128 + (mb * 4 + mi) * 16 + ln) * 640
                              + kt * 32 + q * 8);
#pragma unroll
            for (int j = 0; j < 8; ++j)
              acc[mi][j] = MFMA16(afr, bfr[j], acc[mi][j]);
          }
        }
#pragma unroll
        for (int mi = 0; mi < 4; ++mi)
#pragma unroll
          for (int j = 0; j < 8; ++j)
            *(bf16x4*)(xs + (size_t)((w * 8 + j) * 16 + ln) * 512
                       + mq * 128 + q * 32 + (mb * 4 + mi) * 4) =
                pack4(acc[mi][j] + cb[mb * 4 + mi]);
      }
      __syncthreads();
      if (tid == 0) publish(my, (uint32_t)endk(k));
    }
  } else if (b < 32) {
    // ---- recur layer l: the serial chain. Only w_hh resident. ----
    const int l = (b - 16) >> 2, g = b & 3;
    const bool has_next = (l < 3);
    const bf16_t* whh = (const bf16_t*)(ws + OFF_WHH) + (size_t)l * 512 * 128;
    bf16x8 wfr[8][4];                            // A = w_hh rows w*128+mt*16+ln (128 VGPR)
#pragma unroll
    for (int mt = 0; mt < 8; ++mt)
#pragma unroll
      for (int kt = 0; kt < 4; ++kt)
        wfr[mt][kt] = ldg8(whh + (size_t)(w * 128 + mt * 16 + ln) * 128 + kt * 32 + q * 8);
    float cst[8];
#pragma unroll
    for (int mt = 0; mt < 8; ++mt) cst[mt] = 0.f;
    {
      bf16_t* hz = &hfrag[0][0][0][0];
      for (int i = tid; i < 2 * 4 * 64 * 8; i += 256) hz[i] = (bf16_t)0.f;
    }
    __syncthreads();
    uint32_t* my = cnt + (16 + l * 4 + g) * 16;
    uint32_t* hguard = cnt + (32 + l * 4 + g) * 16;  // gemm_{l+1} progress (yring free)

    bf16_t* hw = &hfrag[0][w][q * 16 + ln][0];       // + buf*2048 elems

    for (int k = 0; k < NCH; ++k) {
      const int t0 = k * CH;
      const int tlen = (T_STEPS - t0 < CH) ? (T_STEPS - t0) : CH;
      if (tid == 0) {
        if (l == 0) {
          for (int mq = 0; mq < 4; ++mq)
            spin_ge(cnt + (mq * 4 + g) * 16, (uint32_t)(t0 + tlen));
        } else {
          spin_ge(cnt + (32 + (l - 1) * 4 + g) * 16, (uint32_t)(t0 + tlen));
        }
        if (has_next && k >= RING) spin_ge(hguard, (uint32_t)endk(k - RING));
        __builtin_amdgcn_fence(__ATOMIC_ACQUIRE, "agent");
      }
      __syncthreads();
      const bf16_t* xin = xring + (size_t)((l * NGR + g) * RING + (k & 3)) * XCH
                          + w * 128 + q * 32;
      bf16_t* yout = yring + (size_t)((l * NGR + g) * RING + (k & 3)) * YSL;  // l<3 only

      bf16x8 xq[4], xqn[4];
#pragma unroll
      for (int i = 0; i < 4; ++i)
        xq[i] = ldg8(xin + (size_t)ln * 512 + i * 8);

#define RSTEP(TREL, BUF)                                                          \
  {                                                                               \
    const int trel_ = (TREL);                                                     \
    if (trel_ + 1 < tlen) {                                                       \
      _Pragma("unroll")                                                           \
      for (int i = 0; i < 4; ++i)                                                 \
        xqn[i] = ldg8(xin + (size_t)((trel_ + 1) * 16 + ln) * 512 + i * 8);       \
    }                                                                             \
    const bf16_t* hr = &hfrag[BUF][0][q * 16 + ln][0];                            \
    bf16x8 hk0 = *(const bf16x8*)(hr);                                            \
    bf16x8 hk1 = *(const bf16x8*)(hr + 512);                                      \
    bf16x8 hk2 = *(const bf16x8*)(hr + 1024);                                     \
    bf16x8 hk3 = *(const bf16x8*)(hr + 1536);                                     \
    f32x4 acc[8];                                                                 \
    _Pragma("unroll")                                                             \
    for (int mt = 0; mt < 8; ++mt) acc[mt] = (f32x4){0.f, 0.f, 0.f, 0.f};         \
    _Pragma("unroll")                                                             \
    for (int mt = 0; mt < 8; ++mt) acc[mt] = MFMA16(wfr[mt][0], hk0, acc[mt]);    \
    _Pragma("unroll")                                                             \
    for (int mt = 0; mt < 8; ++mt) acc[mt] = MFMA16(wfr[mt][1], hk1, acc[mt]);    \
    _Pragma("unroll")                                                             \
    for (int mt = 0; mt < 8; ++mt) acc[mt] = MFMA16(wfr[mt][2], hk2, acc[mt]);    \
    _Pragma("unroll")                                                             \
    for (int mt = 0; mt < 8; ++mt) acc[mt] = MFMA16(wfr[mt][3], hk3, acc[mt]);    \
    bf16x8 hnew;                                                                  \
    _Pragma("unroll")                                                             \
    for (int mt = 0; mt < 8; ++mt) {                                              \
      float p0 = acc[mt][0] + (float)xq[mt >> 1][(mt & 1) * 4 + 0];               \
      float p1 = acc[mt][1] + (float)xq[mt >> 1][(mt & 1) * 4 + 1];               \
      float p2 = acc[mt][2] + (float)xq[mt >> 1][(mt & 1) * 4 + 2];               \
      float p3 = acc[mt][3] + (float)xq[mt >> 1][(mt & 1) * 4 + 3];               \
      float gi = fsigm(p0), gf = fsigm(p1), gg = ftanh(p2), go = fsigm(p3);       \
      cst[mt] = gf * cst[mt] + gi * gg;                                           \
      float hv = go * ftanh(cst[mt]);                                             \
      hnew[mt] = (bf16_t)hv;                                                      \
      if (l == 3 && t0 + trel_ == T_STEPS - 1) hfl[ln][w * 32 + q * 8 + mt] = hv; \
    }                                                                             \
    *(bf16x8*)(hw + ((BUF) ^ 1) * 2048) = hnew;                                   \
    if (has_next)                                                                 \
      *(bf16x8*)(yout + (size_t)((trel_ * 4 + w) * 64 + q * 16 + ln) * 8) = hnew; \
    _Pragma("unroll")                                                             \
    for (int i = 0; i < 4; ++i) xq[i] = xqn[i];                                   \
    asm volatile("s_waitcnt lgkmcnt(0)\n\ts_barrier" ::: "memory");               \
  }

      for (int trel = 0; trel < tlen; trel += 2) {   // tlen always even (32 or 12)
        RSTEP(trel, 0)
        RSTEP(trel + 1, 1)
      }
#undef RSTEP
      __syncthreads();   // drains vmcnt (yring stores) before publishing
      if (tid == 0) publish(my, (uint32_t)(t0 + tlen));
    }

    // ---- fused output head (layer-3 blocks): out = h_fin @ out_w^T + out_b ----
    if (l == 3) {
      __syncthreads();
      for (int i = tid; i < MBB * 48; i += 256) {
        const int b_loc = i / 48, o = i % 48;
        const float* wrow = out_w + (size_t)o * 128;
        float a = out_b[o];
#pragma unroll 4
        for (int j = 0; j < 128; ++j) a += hfl[b_loc][j] * wrow[j];
        out[(size_t)(g * MBB + b_loc) * 48 + o] = a;
      }
    }
  } else {
    // ---- gemm: x_pre_l = W_ih_l @ h_{l-1} (+bias), one chunk behind recur_{l-1} ----
    const int l = 1 + ((b - 32) >> 2), g = b & 3;
    const bf16_t* wih = (const bf16_t*)(ws + OFF_WIH) + (size_t)(l - 1) * 512 * 128;
    bf16x8 wg[8][4];                             // A rows w*128+mt*16+ln (128 VGPR)
#pragma unroll
    for (int mt = 0; mt < 8; ++mt)
#pragma unroll
      for (int kt = 0; kt < 4; ++kt)
        wg[mt][kt] = ldg8(wih + (size_t)(w * 128 + mt * 16 + ln) * 128 + kt * 32 + q * 8);
    f32x4 bg[8];
#pragma unroll
    for (int mt = 0; mt < 8; ++mt)
      bg[mt] = *(const f32x4*)(bias + l * 512 + w * 128 + mt * 16 + q * 4);
    uint32_t* my = cnt + (32 + (l - 1) * 4 + g) * 16;
    uint32_t* xguard = cnt + (16 + l * 4 + g) * 16;   // recur_l progress (xring free)
    for (int k = 0; k < NCH; ++k) {
      const int t0 = k * CH;
      const int tlen = (T_STEPS - t0 < CH) ? (T_STEPS - t0) : CH;
      if (tid == 0) {
        spin_ge(cnt + (16 + (l - 1) * 4 + g) * 16, (uint32_t)(t0 + tlen));  // h ready
        if (k >= RING) spin_ge(xguard, (uint32_t)endk(k - RING));
        __builtin_amdgcn_fence(__ATOMIC_ACQUIRE, "agent");
      }
      __syncthreads();
      const bf16_t* hin = yring + (size_t)(((l - 1) * NGR + g) * RING + (k & 3)) * YSL;
      bf16_t* xs = xring + (size_t)((l * NGR + g) * RING + (k & 3)) * XCH;
      for (int nt = 0; nt < tlen; ++nt) {
        bf16x8 bfr[4];
#pragma unroll
        for (int kt = 0; kt < 4; ++kt)
          bfr[kt] = ldg8(hin + (size_t)((nt * 4 + kt) * 64 + lane) * 8);
        f32x4 acc[8];
#pragma unroll
        for (int mt = 0; mt < 8; ++mt) acc[mt] = (f32x4){0.f, 0.f, 0.f, 0.f};
#pragma unroll
        for (int kt = 0; kt < 4; ++kt)
#pragma unroll
          for (int mt = 0; mt < 8; ++mt)
            acc[mt] = MFMA16(wg[mt][kt], bfr[kt], acc[mt]);
#pragma unroll
        for (int mt = 0; mt < 8; ++mt)
          *(bf16x4*)(xs + (size_t)(nt * 16 + ln) * 512 + w * 128 + q * 32 + mt * 4) =
              pack4(acc[mt] + bg[mt]);
      }
      __syncthreads();
      if (tid == 0) publish(my, (uint32_t)(t0 + tlen));
    }
  }
}

extern "C" void kernel_launch(void* const* d_in, const int* in_sizes, int n_in,
                              void* d_out, int out_size, void* d_ws, size_t ws_size,
                              hipStream_t stream) {
  (void)in_sizes; (void)n_in; (void)out_size; (void)ws_size;
  const float* inputs    = (const float*)d_in[0];
  const float* proj_w    = (const float*)d_in[4];
  const float* proj_b    = (const float*)d_in[5];
  const float* w_ih0     = (const float*)d_in[6];
  const float* w_hh0     = (const float*)d_in[7];
  const float* b_ih0     = (const float*)d_in[8];
  const float* b_hh0     = (const float*)d_in[9];
  const float* w_ih_rest = (const float*)d_in[10];
  const float* w_hh_rest = (const float*)d_in[11];
  const float* b_ih_rest = (const float*)d_in[12];
  const float* b_hh_rest = (const float*)d_in[13];
  const float* out_w     = (const float*)d_in[14];
  const float* out_b     = (const float*)d_in[15];
  uint8_t* ws = (uint8_t*)d_ws;
  float* out = (float*)d_out;

  k_prep_misc<<<dim3(2048), dim3(128), 0, stream>>>(w_hh0, w_ih_rest, w_hh_rest,
                                                    b_ih_rest, b_hh_rest, ws);
  k_prep_effw<<<dim3(512), dim3(256), 0, stream>>>(proj_w, proj_b, w_ih0, b_ih0, b_hh0, ws);
  k_pipeline<<<dim3(44), dim3(256), 0, stream>>>(inputs, out_w, out_b, out, ws);
}

// Round 8
// 3469.435 us; speedup vs baseline: 2.0940x; 2.0940x over previous
//
#include <hip/hip_runtime.h>
#include <stdint.h>
#include <stddef.h>

typedef __bf16 bf16_t;
typedef bf16_t bf16x8 __attribute__((ext_vector_type(8)));
typedef bf16_t bf16x4 __attribute__((ext_vector_type(4)));
typedef float  f32x4  __attribute__((ext_vector_type(4)));

#define T_STEPS 2028
#define SEQ     2048
#define CIN     32
#define NG      32     // batch groups
#define MB      2      // batch per group
#define CH      32     // chunk steps
#define NCH     64     // ceil(2028/32)
#define RING    4      // ring depth in chunks
#define XSL     (CH*2*512)   // bf16 elems per xring slot: [32 steps][2 b][512 gate-rows]

// workspace layout (bytes); ~35 MB
#define OFF_EFFW   0u          // bf16 [512][640]  (permuted gate rows)
#define OFF_BIAS   655360u     // f32  [4][512]    (permuted; l0 includes proj_b@w_ih0)
#define OFF_WHH    663552u     // bf16 [4][512][128] (permuted)
#define OFF_WIH    1187840u    // bf16 [3][512][128] (permuted, layers 1..3)
#define OFF_CNT    1613824u    // u32  counters, 64B-strided
#define OFF_XRING  1638400u    // bf16 [4 layers][NG][RING][XSL]

// permuted gate row p = 4*unit + gate  ->  original LSTM row gate*128 + unit.
// D-tile then gives lane (q,ln) of wave w, tile mt: acc[mt][r] = gate r of unit
// w*32+mt*4+q, batch ln&1 (B columns replicated by batch = col&1). Lane activates
// mt_own = ln>>1  ->  exactly one (unit,batch) per thread, NO gate_buf LDS bounce.
__device__ __host__ __forceinline__ int orig_row(int p) {
  return (p & 3) * 128 + (p >> 2);
}

__device__ __forceinline__ int endk(int k) {
  int e = (k + 1) * CH;
  return e > T_STEPS ? T_STEPS : e;
}

__device__ __forceinline__ void spin_ge(uint32_t* p, uint32_t tgt) {
  while (atomicAdd(p, 0u) < tgt) __builtin_amdgcn_s_sleep(2);
}
__device__ __forceinline__ void publish(uint32_t* p, uint32_t v) {
  __builtin_amdgcn_fence(__ATOMIC_RELEASE, "agent");
  atomicMax(p, v);
}

__device__ __forceinline__ float fsigm(float x) {
  return __builtin_amdgcn_rcpf(1.0f + __builtin_amdgcn_exp2f(x * -1.44269504089f));
}
__device__ __forceinline__ float ftanh(float x) {
  return 1.0f - 2.0f * __builtin_amdgcn_rcpf(1.0f + __builtin_amdgcn_exp2f(x * 2.88539008178f));
}

__device__ __forceinline__ bf16x8 ldg8(const bf16_t* p) { return *(const bf16x8*)p; }
__device__ __forceinline__ bf16x4 ldg4(const bf16_t* p) { return *(const bf16x4*)p; }

__device__ __forceinline__ bf16x8 ldg_cvt8(const float* p) {
  const f32x4 a = *(const f32x4*)p;
  const f32x4 b = *(const f32x4*)(p + 4);
  bf16x8 r;
  r[0] = (bf16_t)a[0]; r[1] = (bf16_t)a[1]; r[2] = (bf16_t)a[2]; r[3] = (bf16_t)a[3];
  r[4] = (bf16_t)b[0]; r[5] = (bf16_t)b[1]; r[6] = (bf16_t)b[2]; r[7] = (bf16_t)b[3];
  return r;
}

__device__ __forceinline__ bf16x4 pack4(f32x4 a) {
  bf16x4 v;
  v[0] = (bf16_t)a[0]; v[1] = (bf16_t)a[1]; v[2] = (bf16_t)a[2]; v[3] = (bf16_t)a[3];
  return v;
}

#define MFMA16(a, b, c) __builtin_amdgcn_mfma_f32_16x16x32_bf16((a), (b), (c), 0, 0, 0)

// ---------------- prep: permute weights, biases, zero counters ----------------
__global__ void k_prep_misc(const float* __restrict__ w_hh0,
                            const float* __restrict__ w_ih_rest,
                            const float* __restrict__ w_hh_rest,
                            const float* __restrict__ b_ih_rest,
                            const float* __restrict__ b_hh_rest,
                            uint8_t* __restrict__ ws) {
  const int bid = blockIdx.x;          // 2048 blocks
  const int l = bid >> 9;              // 0..3
  const int p = bid & 511;
  const int orig = orig_row(p);
  const int tid = threadIdx.x;         // 128 threads
  bf16_t* whh = (bf16_t*)(ws + OFF_WHH);
  bf16_t* wih = (bf16_t*)(ws + OFF_WIH);
  float* bias = (float*)(ws + OFF_BIAS);
  const float* src = (l == 0) ? (w_hh0 + orig * 128)
                              : (w_hh_rest + ((size_t)(l - 1) * 512 + orig) * 128);
  whh[((size_t)l * 512 + p) * 128 + tid] = (bf16_t)src[tid];
  if (l < 3)
    wih[((size_t)l * 512 + p) * 128 + tid] = (bf16_t)w_ih_rest[((size_t)l * 512 + orig) * 128 + tid];
  if (l >= 1 && tid == 0)
    bias[l * 512 + p] = b_ih_rest[(l - 1) * 512 + orig] + b_hh_rest[(l - 1) * 512 + orig];
  if (bid == 0) {
    uint32_t* cnt = (uint32_t*)(ws + OFF_CNT);
    for (int i = tid; i < 12 * 32 * 16; i += 128) cnt[i] = 0;
  }
}

// eff_w = w_ih0 @ proj_w (fused proj+layer0-input), eff_b -> bias[0]
__global__ void k_prep_effw(const float* __restrict__ proj_w,
                            const float* __restrict__ proj_b,
                            const float* __restrict__ w_ih0,
                            const float* __restrict__ b_ih0,
                            const float* __restrict__ b_hh0,
                            uint8_t* __restrict__ ws) {
  __shared__ float wr[320];
  const int p = blockIdx.x;            // 512 blocks
  const int orig = orig_row(p);
  const int tid = threadIdx.x;         // 256 threads
  for (int i = tid; i < 320; i += 256) wr[i] = w_ih0[(size_t)orig * 320 + i];
  __syncthreads();
  bf16_t* effw = (bf16_t*)(ws + OFF_EFFW);
  for (int kk = tid; kk < 640; kk += 256) {
    float a = 0.f;
    for (int z = 0; z < 320; ++z) a += wr[z] * proj_w[(size_t)z * 640 + kk];
    effw[(size_t)p * 640 + kk] = (bf16_t)a;
  }
  if (tid == 0) {
    float a = 0.f;
    for (int z = 0; z < 320; ++z) a += wr[z] * proj_b[z];
    ((float*)(ws + OFF_BIAS))[p] = a + b_ih0[orig] + b_hh0[orig];
  }
}

// ---------------- 5-stage persistent pipeline, replicated-column D-tiles ----------------
// 160 blocks x 256 threads. s = blockIdx>>5: 0=conv, 1..4=recur l=s-1 ; g = blockIdx&31.
// recur: B columns replicated (col c = batch c&1), so each lane's acc[ln>>1] is the full
// 4-gate vector of its own (unit,batch) -> in-lane activation via a 7-select cndmask tree.
// h lives compactly in hbuf[2][2][128] (1 ds_write_b16/lane; broadcast b128 reads).
// x_pre for layer l+1 fused (lanes ln<2 store it); per-chunk flush covers the last step.
__global__ __launch_bounds__(256, 1) void k_pipeline(const float* __restrict__ in,
                                                     const float* __restrict__ out_w,
                                                     const float* __restrict__ out_b,
                                                     float* __restrict__ out,
                                                     uint8_t* __restrict__ ws) {
  __shared__ __align__(16) bf16_t hbuf[2][2][128];   // [buf][batch][unit]
  __shared__ float hfl[2][128];                      // final h for output head

  const int s = blockIdx.x >> 5;
  const int g = blockIdx.x & 31;
  const int tid = threadIdx.x;
  const int w = tid >> 6;              // wave 0..3
  const int lane = tid & 63;
  const int q = lane >> 4;             // 0..3
  const int ln = lane & 15;            // 0..15

  uint32_t* cnt = (uint32_t*)(ws + OFF_CNT);
  bf16_t* xring = (bf16_t*)(ws + OFF_XRING);

  if (s == 0) {
    // ---- conv: windows @ eff_w^T -> xring0 (replicated-column layout) ----
    const bf16_t* effw = (const bf16_t*)(ws + OFF_EFFW);
    uint32_t* my = cnt + (0 * NG + g) * 16;
    uint32_t* guard = cnt + (1 * NG + g) * 16;   // recur0 progress (ring free)
    const int bb = ln & 1;                       // batch of this column
    const int tsub = ln >> 1;                    // step-within-8 of this column
    for (int k = 0; k < NCH; ++k) {
      if (tid == 0 && k >= RING) spin_ge(guard, (uint32_t)endk(k - RING));
      __syncthreads();
      const int t0 = k * CH;
      f32x4 acc[8][4];                           // [mi][j]
#pragma unroll
      for (int mi = 0; mi < 8; ++mi)
#pragma unroll
        for (int j = 0; j < 4; ++j) acc[mi][j] = (f32x4){0.f, 0.f, 0.f, 0.f};
#pragma unroll 4
      for (int kt = 0; kt < 20; ++kt) {          // kt == window offset
        bf16x8 bfr[4];
#pragma unroll
        for (int j = 0; j < 4; ++j) {
          int tt = t0 + j * 8 + tsub;
          if (tt > T_STEPS - 1) tt = T_STEPS - 1;
          bfr[j] = ldg_cvt8(in + (size_t)((g * MB + bb) * SEQ + tt + kt) * CIN + q * 8);
        }
#pragma unroll
        for (int mi = 0; mi < 8; ++mi) {
          bf16x8 afr = ldg8(effw + (size_t)(w * 128 + mi * 16 + ln) * 640 + kt * 32 + q * 8);
#pragma unroll
          for (int j = 0; j < 4; ++j)
            acc[mi][j] = MFMA16(afr, bfr[j], acc[mi][j]);
        }
      }
      bf16_t* xs = xring + (size_t)((0 * NG + g) * RING + (k & 3)) * XSL;
#pragma unroll
      for (int mi = 0; mi < 8; ++mi)
#pragma unroll
        for (int j = 0; j < 4; ++j) {
          const int trel = j * 8 + tsub;
          const int u = w * 32 + mi * 4 + q;
          *(bf16x4*)(xs + (size_t)(trel * 2 + bb) * 512 + u * 4) = pack4(acc[mi][j]);
        }
      __syncthreads();
      if (tid == 0) publish(my, (uint32_t)endk(k));
    }
  } else {
    // ---- recur layer l (+ fused x_pre for layer l+1) ----
    const int l = s - 1;
    const bool has_next = (l < 3);
    const bf16_t* whh = (const bf16_t*)(ws + OFF_WHH) + (size_t)l * 512 * 128;
    bf16x8 wfr[8][4];                            // A = w_hh rows w*128+mt*16+ln
#pragma unroll
    for (int mt = 0; mt < 8; ++mt)
#pragma unroll
      for (int kt = 0; kt < 4; ++kt)
        wfr[mt][kt] = ldg8(whh + (size_t)(w * 128 + mt * 16 + ln) * 128 + kt * 32 + q * 8);
    bf16x8 wnx[8][4];                            // A = w_ih_{l+1}
    if (has_next) {
      const bf16_t* wih = (const bf16_t*)(ws + OFF_WIH) + (size_t)l * 512 * 128;
#pragma unroll
      for (int mt = 0; mt < 8; ++mt)
#pragma unroll
        for (int kt = 0; kt < 4; ++kt)
          wnx[mt][kt] = ldg8(wih + (size_t)(w * 128 + mt * 16 + ln) * 128 + kt * 32 + q * 8);
    }
    const int b_own = ln & 1;
    const int u_own = w * 32 + (ln >> 1) * 4 + q;
    const bool t1 = (ln & 2) != 0, t2 = (ln & 4) != 0, t3 = (ln & 8) != 0;
    f32x4 biasq = *(const f32x4*)((const float*)(ws + OFF_BIAS) + l * 512 + u_own * 4);
    float c = 0.f;
    {
      bf16_t* hz = &hbuf[0][0][0];
      for (int i = tid; i < 2 * 2 * 128; i += 256) hz[i] = (bf16_t)0.f;
    }
    __syncthreads();
    uint32_t* my = cnt + ((1 + l) * NG + g) * 16;
    uint32_t* prod = cnt + (l * NG + g) * 16;         // conv (l==0) or recur_{l-1}
    uint32_t* xguard = cnt + ((2 + l) * NG + g) * 16; // recur_{l+1} progress (ring free)

    for (int k = 0; k < NCH; ++k) {
      const int t0 = k * CH;
      const int tlen = (T_STEPS - t0 < CH) ? (T_STEPS - t0) : CH;
      if (tid == 0) {
        spin_ge(prod, (uint32_t)(t0 + tlen));
        if (has_next && k >= RING) spin_ge(xguard, (uint32_t)endk(k - RING));
        __builtin_amdgcn_fence(__ATOMIC_ACQUIRE, "agent");
      }
      __syncthreads();
      const bf16_t* xin = xring + (size_t)((l * NG + g) * RING + (k & 3)) * XSL
                          + b_own * 512 + u_own * 4;
      bf16_t* xout = xring + (size_t)(((has_next ? l + 1 : l) * NG + g) * RING + (k & 3)) * XSL;

      bf16x4 xq = ldg4(xin), xqn;
#pragma unroll 2
      for (int trel = 0; trel < tlen; ++trel) {
        const int buf = trel & 1;                // t0 even -> parity continuous
        if (trel + 1 < tlen) xqn = ldg4(xin + (size_t)(trel + 1) * 1024);
        const bf16_t* hb = &hbuf[buf][b_own][0];
        bf16x8 hk0 = *(const bf16x8*)(hb + q * 8);
        bf16x8 hk1 = *(const bf16x8*)(hb + 32 + q * 8);
        bf16x8 hk2 = *(const bf16x8*)(hb + 64 + q * 8);
        bf16x8 hk3 = *(const bf16x8*)(hb + 96 + q * 8);
        f32x4 acc[8];
#pragma unroll
        for (int mt = 0; mt < 8; ++mt) acc[mt] = (f32x4){0.f, 0.f, 0.f, 0.f};
#pragma unroll
        for (int mt = 0; mt < 8; ++mt) acc[mt] = MFMA16(wfr[mt][0], hk0, acc[mt]);
#pragma unroll
        for (int mt = 0; mt < 8; ++mt) acc[mt] = MFMA16(wfr[mt][1], hk1, acc[mt]);
#pragma unroll
        for (int mt = 0; mt < 8; ++mt) acc[mt] = MFMA16(wfr[mt][2], hk2, acc[mt]);
#pragma unroll
        for (int mt = 0; mt < 8; ++mt) acc[mt] = MFMA16(wfr[mt][3], hk3, acc[mt]);
        // fused x_pre_{l+1}[trel-1] (same h operand); lanes ln<2 store it
        if (has_next && trel) {
          f32x4 a2[8];
#pragma unroll
          for (int mt = 0; mt < 8; ++mt) a2[mt] = (f32x4){0.f, 0.f, 0.f, 0.f};
#pragma unroll
          for (int mt = 0; mt < 8; ++mt) a2[mt] = MFMA16(wnx[mt][0], hk0, a2[mt]);
#pragma unroll
          for (int mt = 0; mt < 8; ++mt) a2[mt] = MFMA16(wnx[mt][1], hk1, a2[mt]);
#pragma unroll
          for (int mt = 0; mt < 8; ++mt) a2[mt] = MFMA16(wnx[mt][2], hk2, a2[mt]);
#pragma unroll
          for (int mt = 0; mt < 8; ++mt) a2[mt] = MFMA16(wnx[mt][3], hk3, a2[mt]);
          if (ln < MB) {
#pragma unroll
            for (int mt = 0; mt < 8; ++mt)
              *(bf16x4*)(xout + (size_t)((trel - 1) * 2 + ln) * 512
                         + (w * 32 + mt * 4 + q) * 4) = pack4(a2[mt]);
          }
        }
        // in-lane gate select (7-select cndmask tree) + activation for (u_own, b_own)
        f32x4 g01 = t1 ? acc[1] : acc[0];
        f32x4 g23 = t1 ? acc[3] : acc[2];
        f32x4 g45 = t1 ? acc[5] : acc[4];
        f32x4 g67 = t1 ? acc[7] : acc[6];
        f32x4 g03 = t2 ? g23 : g01;
        f32x4 g47 = t2 ? g67 : g45;
        f32x4 gsel = t3 ? g47 : g03;
        float p0 = gsel[0] + (float)xq[0] + biasq[0];
        float p1 = gsel[1] + (float)xq[1] + biasq[1];
        float p2 = gsel[2] + (float)xq[2] + biasq[2];
        float p3 = gsel[3] + (float)xq[3] + biasq[3];
        float gi = fsigm(p0), gf = fsigm(p1), gg = ftanh(p2), go = fsigm(p3);
        c = gf * c + gi * gg;
        float hv = go * ftanh(c);
        hbuf[buf ^ 1][b_own][u_own] = (bf16_t)hv;
        if (l == 3 && t0 + trel == T_STEPS - 1) hfl[b_own][u_own] = hv;
        xq = xqn;
        asm volatile("s_waitcnt lgkmcnt(0)\n\ts_barrier" ::: "memory");
      }
      // ---- flush: x_pre_{l+1}[t0+tlen-1] from h[t0+tlen-1] (in hbuf[0], tlen even) ----
      if (has_next) {
        const bf16_t* hb = &hbuf[0][b_own][0];
        bf16x8 f0 = *(const bf16x8*)(hb + q * 8);
        bf16x8 f1 = *(const bf16x8*)(hb + 32 + q * 8);
        bf16x8 f2 = *(const bf16x8*)(hb + 64 + q * 8);
        bf16x8 f3 = *(const bf16x8*)(hb + 96 + q * 8);
        f32x4 a2[8];
#pragma unroll
        for (int mt = 0; mt < 8; ++mt) a2[mt] = (f32x4){0.f, 0.f, 0.f, 0.f};
#pragma unroll
        for (int mt = 0; mt < 8; ++mt) {
          a2[mt] = MFMA16(wnx[mt][0], f0, a2[mt]);
          a2[mt] = MFMA16(wnx[mt][1], f1, a2[mt]);
          a2[mt] = MFMA16(wnx[mt][2], f2, a2[mt]);
          a2[mt] = MFMA16(wnx[mt][3], f3, a2[mt]);
        }
        if (ln < MB) {
#pragma unroll
          for (int mt = 0; mt < 8; ++mt)
            *(bf16x4*)(xout + (size_t)((tlen - 1) * 2 + ln) * 512
                       + (w * 32 + mt * 4 + q) * 4) = pack4(a2[mt]);
        }
      }
      __syncthreads();   // drains vmcnt in every wave before publishing
      if (tid == 0) publish(my, (uint32_t)(t0 + tlen));
    }

    // ---- fused output head (layer-3 blocks): out = h_fin @ out_w^T + out_b ----
    if (l == 3) {
      __syncthreads();
      if (tid < 96) {                  // 2 batches x 48 outputs per group
        const int b_loc = tid / 48, o = tid % 48;
        const float* wrow = out_w + (size_t)o * 128;
        float a = out_b[o];
#pragma unroll 4
        for (int j = 0; j < 128; ++j) a += hfl[b_loc][j] * wrow[j];
        out[(size_t)(g * MB + b_loc) * 48 + o] = a;
      }
    }
  }
}

extern "C" void kernel_launch(void* const* d_in, const int* in_sizes, int n_in,
                              void* d_out, int out_size, void* d_ws, size_t ws_size,
                              hipStream_t stream) {
  (void)in_sizes; (void)n_in; (void)out_size; (void)ws_size;
  const float* inputs    = (const float*)d_in[0];
  const float* proj_w    = (const float*)d_in[4];
  const float* proj_b    = (const float*)d_in[5];
  const float* w_ih0     = (const float*)d_in[6];
  const float* w_hh0     = (const float*)d_in[7];
  const float* b_ih0     = (const float*)d_in[8];
  const float* b_hh0     = (const float*)d_in[9];
  const float* w_ih_rest = (const float*)d_in[10];
  const float* w_hh_rest = (const float*)d_in[11];
  const float* b_ih_rest = (const float*)d_in[12];
  const float* b_hh_rest = (const float*)d_in[13];
  const float* out_w     = (const float*)d_in[14];
  const float* out_b     = (const float*)d_in[15];
  uint8_t* ws = (uint8_t*)d_ws;
  float* out = (float*)d_out;

  k_prep_misc<<<dim3(2048), dim3(128), 0, stream>>>(w_hh0, w_ih_rest, w_hh_rest,
                                                    b_ih_rest, b_hh_rest, ws);
  k_prep_effw<<<dim3(512), dim3(256), 0, stream>>>(proj_w, proj_b, w_ih0, b_ih0, b_hh0, ws);
  k_pipeline<<<dim3(160), dim3(256), 0, stream>>>(inputs, out_w, out_b, out, ws);
}